// Round 8
// baseline (242.709 us; speedup 1.0000x reference)
//
#include <hip/hip_runtime.h>
#include <hip/hip_bf16.h>
#include <math.h>

// DiceLoss: B=8, C=19, H=W=512. logits fp32 [B,C,H,W], targets int [B,H,W].
// Round 8: software-pipelined register double-buffer. Iteration k+1's 19
// nt float4 loads are issued BEFORE computing iteration k (vmcnt is in-order,
// so buffer-k waits don't stall on buffer-k+1 loads). Each wave keeps ~5 KB
// in flight during compute; 8 waves/CU -> ~40 KB/CU in flight (>21.6 KB
// needed for 6 TB/s at 900 cy latency). 512 blocks, 4 iters/thread.

#define CC 19
#define HWBITS 18
#define HHWW (1 << HWBITS)            // 262144
#define NPIX (8 * HHWW)               // 2,097,152
#define QPP (HHWW / 4)                // 65536 float4-quads per channel plane
#define NQUAD (NPIX / 4)              // 524288
#define NBLK 512
#define NTHR 256
#define NTH_TOT (NBLK * NTHR)         // 131072
#define NITER (NQUAD / NTH_TOT)       // 4, exact
#define IGNORE_IDX 255

typedef float f32x4 __attribute__((ext_vector_type(4)));
typedef int   i32x4 __attribute__((ext_vector_type(4)));

#define LOADQ(X, T, IT) do {                                                  \
    const int q_ = tid + (IT) * NTH_TOT;                                      \
    const int b_ = q_ >> 16;                                                  \
    const int hw4_ = q_ & (QPP - 1);                                          \
    const f32x4* base_ = (const f32x4*)logits + (size_t)(b_ * CC) * QPP + hw4_; \
    _Pragma("unroll")                                                         \
    for (int c = 0; c < CC; ++c)                                              \
        X[c] = __builtin_nontemporal_load(base_ + (size_t)c * QPP);           \
    T = __builtin_nontemporal_load((const i32x4*)(targets + 4 * (size_t)q_)); \
} while (0)

#define COMPUTE(X, T) do {                                                    \
    float s0 = 0.f, s1 = 0.f, s2 = 0.f, s3 = 0.f;                             \
    _Pragma("unroll")                                                         \
    for (int c = 0; c < CC; ++c) {                                            \
        X[c].x = __expf(X[c].x); s0 += X[c].x;                                \
        X[c].y = __expf(X[c].y); s1 += X[c].y;                                \
        X[c].z = __expf(X[c].z); s2 += X[c].z;                                \
        X[c].w = __expf(X[c].w); s3 += X[c].w;                                \
    }                                                                         \
    const float i0 = (T.x != IGNORE_IDX) ? __builtin_amdgcn_rcpf(s0) : 0.f;   \
    const float i1 = (T.y != IGNORE_IDX) ? __builtin_amdgcn_rcpf(s1) : 0.f;   \
    const float i2 = (T.z != IGNORE_IDX) ? __builtin_amdgcn_rcpf(s2) : 0.f;   \
    const float i3 = (T.w != IGNORE_IDX) ? __builtin_amdgcn_rcpf(s3) : 0.f;   \
    _Pragma("unroll")                                                         \
    for (int c = 0; c < CC; ++c) {                                            \
        accS[c] = fmaf(X[c].x, i0,                                            \
                  fmaf(X[c].y, i1,                                            \
                  fmaf(X[c].z, i2,                                            \
                  fmaf(X[c].w, i3, accS[c]))));                               \
        const bool h0 = (T.x == c), h1 = (T.y == c);                          \
        const bool h2 = (T.z == c), h3 = (T.w == c);                          \
        accI[c] = fmaf(h0 ? X[c].x : 0.f, i0,                                 \
                  fmaf(h1 ? X[c].y : 0.f, i1,                                 \
                  fmaf(h2 ? X[c].z : 0.f, i2,                                 \
                  fmaf(h3 ? X[c].w : 0.f, i3, accI[c]))));                    \
        accC[c] += (h0 ? 1.f : 0.f) + (h1 ? 1.f : 0.f)                        \
                 + (h2 ? 1.f : 0.f) + (h3 ? 1.f : 0.f);                       \
    }                                                                         \
} while (0)

__global__ __launch_bounds__(NTHR, 2) void dice_accum(
    const float* __restrict__ logits,
    const int* __restrict__ targets,
    float* __restrict__ part)         // part[NBLK][64]: 0-18 S, 19-37 I, 38-56 cnt
{
    const int tid = blockIdx.x * NTHR + threadIdx.x;

    float accS[CC], accI[CC], accC[CC];
#pragma unroll
    for (int c = 0; c < CC; ++c) { accS[c] = 0.f; accI[c] = 0.f; accC[c] = 0.f; }

    f32x4 xa[CC], xb[CC];
    i32x4 ta, tb;

    // software pipeline: issue next batch before computing current
    LOADQ(xa, ta, 0);
    LOADQ(xb, tb, 1);
    COMPUTE(xa, ta);
    LOADQ(xa, ta, 2);
    COMPUTE(xb, tb);
    LOADQ(xb, tb, 3);
    COMPUTE(xa, ta);
    COMPUTE(xb, tb);

    // ---- wave-level reduce of the 57 accumulators ----
#pragma unroll
    for (int c = 0; c < CC; ++c) {
        for (int off = 32; off; off >>= 1) {
            accS[c] += __shfl_down(accS[c], off);
            accI[c] += __shfl_down(accI[c], off);
            accC[c] += __shfl_down(accC[c], off);
        }
    }

    __shared__ float s_part[4][64];
    const int wave = threadIdx.x >> 6;
    const int lane = threadIdx.x & 63;
    if (lane == 0) {
#pragma unroll
        for (int c = 0; c < CC; ++c) {
            s_part[wave][c]          = accS[c];
            s_part[wave][CC + c]     = accI[c];
            s_part[wave][2 * CC + c] = accC[c];
        }
#pragma unroll
        for (int c = 3 * CC; c < 64; ++c) s_part[wave][c] = 0.f;  // ws is poisoned
    }
    __syncthreads();
    if (threadIdx.x < 64) {
        float v = s_part[0][threadIdx.x] + s_part[1][threadIdx.x]
                + s_part[2][threadIdx.x] + s_part[3][threadIdx.x];
        part[blockIdx.x * 64 + threadIdx.x] = v;
    }
}

__global__ __launch_bounds__(1024) void dice_final(
    const float* __restrict__ part, float* __restrict__ out)
{
    const int wave = threadIdx.x >> 6;   // 0..15
    const int lane = threadIdx.x & 63;
    float v = 0.f;
    for (int r = wave; r < NBLK; r += 16)
        v += part[r * 64 + lane];        // coalesced 256B rows

    __shared__ float s_red[16][64];
    s_red[wave][lane] = v;
    __syncthreads();

    __shared__ float s_tot[64];
    if (threadIdx.x < 64) {
        float tot = 0.f;
#pragma unroll
        for (int w = 0; w < 16; ++w) tot += s_red[w][threadIdx.x];
        s_tot[threadIdx.x] = tot;
    }
    __syncthreads();

    if (threadIdx.x == 0) {
        float loss = 0.f, totv = 0.f;
#pragma unroll
        for (int c = 0; c < CC; ++c) {
            const float S = s_tot[c];
            const float I = s_tot[CC + c];
            const float N = s_tot[2 * CC + c];
            totv += N;
            loss += 1.f - (2.f * I + 1.f) / (S + N + 1.f);
        }
        out[0] = (totv > 0.f) ? loss * (1.f / (float)CC) : 0.f;
    }
}

extern "C" void kernel_launch(void* const* d_in, const int* in_sizes, int n_in,
                              void* d_out, int out_size, void* d_ws, size_t ws_size,
                              hipStream_t stream) {
    const float* logits = (const float*)d_in[0];
    const int* targets = (const int*)d_in[1];
    float* part = (float*)d_ws;          // 512*64*4 = 128 KB
    float* out = (float*)d_out;

    dice_accum<<<NBLK, NTHR, 0, stream>>>(logits, targets, part);
    dice_final<<<1, 1024, 0, stream>>>(part, out);
}